// Round 6
// baseline (3028.353 us; speedup 1.0000x reference)
//
#include <hip/hip_runtime.h>
#include <hip/hip_bf16.h>
#include <hip/hip_cooperative_groups.h>
#include <math.h>

namespace cg = cooperative_groups;

// ---------------------------------------------------------------------------
// B=32, N=128, D=5000, H=256, C=4
//   1) x_tilde = x @ Er^T                      (gemm_nt fp32)
//   2) P = x_tilde @ {6 W}^T  (6 gemm_nt launches)
//   3) UTb = bf16-packed transposed U: uint4 = 8 j-values for fixed h
//   4) build_schedule: counting-sort nodes by tree depth
//   5) tree_scan_lp: cooperative 256 WGs x 1024 thr; 4 subgroups/WG (4 waves/
//      SIMD for latency hiding), each subgroup = R5-proven TPB=4 node batch
//   6) epilogue
// ---------------------------------------------------------------------------

#define H_DIM 256
#define N_NODES 128
#define B_TREES 32
#define MAXL 128
#define TPB 4
#define NSG 4
#define GRID_WGS 256

__device__ __forceinline__ float sigmoidf_(float x) {
    return 1.0f / (1.0f + expf(-x));
}
__device__ __forceinline__ unsigned bfp(float x) {  // fp32 -> bf16 bits (RNE)
    unsigned u = __float_as_uint(x);
    return (u + 0x7fffu + ((u >> 16) & 1u)) >> 16;
}
__device__ __forceinline__ float bflo(unsigned w) { return __uint_as_float(w << 16); }
__device__ __forceinline__ float bfhi(unsigned w) { return __uint_as_float(w & 0xffff0000u); }

__device__ __forceinline__ void unpack8(uint4 v, float* f) {
    f[0] = bflo(v.x); f[1] = bfhi(v.x);
    f[2] = bflo(v.y); f[3] = bfhi(v.y);
    f[4] = bflo(v.z); f[5] = bfhi(v.z);
    f[6] = bflo(v.w); f[7] = bfhi(v.w);
}

// C[M,N] = A[M,K] @ B[N,K]^T   (row-major, K contiguous; M,N mult of 64)
__global__ __launch_bounds__(256) void gemm_nt(
    const float* __restrict__ A, const float* __restrict__ B,
    float* __restrict__ C, int K, int ldc) {
    __shared__ float As[64][68];
    __shared__ float Bs[64][68];
    const int tid = threadIdx.x;
    const int bm = blockIdx.x, bn = blockIdx.y;
    const int tx = tid & 15, ty = tid >> 4;
    float acc[4][4] = {{0.f}};
    const int nk = (K + 63) >> 6;
    for (int kt = 0; kt < nk; ++kt) {
        const int k0 = kt << 6;
#pragma unroll
        for (int it = 0; it < 4; ++it) {
            const int f = tid + it * 256;
            const int row = f >> 4;
            const int cq = f & 15;
            const int kcol = k0 + cq * 4;
            float4 av = make_float4(0.f, 0.f, 0.f, 0.f);
            float4 bv = make_float4(0.f, 0.f, 0.f, 0.f);
            if (kcol < K) {
                av = *(const float4*)(A + (size_t)(bm * 64 + row) * K + kcol);
                bv = *(const float4*)(B + (size_t)(bn * 64 + row) * K + kcol);
            }
            *(float4*)&As[row][cq * 4] = av;
            *(float4*)&Bs[row][cq * 4] = bv;
        }
        __syncthreads();
#pragma unroll 4
        for (int kk = 0; kk < 64; kk += 4) {
            float4 a[4], bq[4];
#pragma unroll
            for (int i = 0; i < 4; ++i) a[i] = *(const float4*)&As[ty * 4 + i][kk];
#pragma unroll
            for (int j = 0; j < 4; ++j) bq[j] = *(const float4*)&Bs[tx * 4 + j][kk];
#pragma unroll
            for (int i = 0; i < 4; ++i)
#pragma unroll
                for (int j = 0; j < 4; ++j)
                    acc[i][j] += a[i].x * bq[j].x + a[i].y * bq[j].y +
                                 a[i].z * bq[j].z + a[i].w * bq[j].w;
        }
        __syncthreads();
    }
#pragma unroll
    for (int i = 0; i < 4; ++i) {
        float4 o = make_float4(acc[i][0], acc[i][1], acc[i][2], acc[i][3]);
        *(float4*)(C + (size_t)(bm * 64 + ty * 4 + i) * ldc + bn * 64 + tx * 4) = o;
    }
}

// UTb[(m*32 + jblk)*256 + h] = uint4 of 8 bf16 = U_m[h][8*jblk .. 8*jblk+7]
__global__ __launch_bounds__(256) void transpose_pack_u(
    const float* __restrict__ U0, const float* __restrict__ U1,
    const float* __restrict__ U2, const float* __restrict__ U3,
    const float* __restrict__ U4, const float* __restrict__ U5,
    const float* __restrict__ U6, const float* __restrict__ U7,
    const float* __restrict__ U8, uint4* __restrict__ UTb) {
    const float* Us[9] = {U0, U1, U2, U3, U4, U5, U6, U7, U8};
    const int jb = blockIdx.x;     // 0..31
    const int m = blockIdx.y;      // 0..8
    const int h = threadIdx.x;     // 0..255
    const float* U = Us[m] + (size_t)h * 256 + jb * 8;
    uint4 v;
    v.x = bfp(U[0]) | (bfp(U[1]) << 16);
    v.y = bfp(U[2]) | (bfp(U[3]) << 16);
    v.z = bfp(U[4]) | (bfp(U[5]) << 16);
    v.w = bfp(U[6]) | (bfp(U[7]) << 16);
    UTb[(size_t)(m * 32 + jb) * 256 + h] = v;
}

__global__ __launch_bounds__(256) void build_schedule(
    const int* __restrict__ parents, int* __restrict__ sched,
    int* __restrict__ level_off) {
    __shared__ unsigned char depth[B_TREES][N_NODES];
    __shared__ int counts[MAXL];
    __shared__ int base[MAXL + 1];
    const int tid = threadIdx.x;
    for (int k = tid; k < MAXL; k += 256) counts[k] = 0;
    __syncthreads();
    if (tid < B_TREES) {
        depth[tid][0] = 0;
        for (int i = 1; i < N_NODES; ++i) {
            const int p = parents[tid * N_NODES + i];
            depth[tid][i] = (unsigned char)(depth[tid][p - 1] + 1);
        }
    }
    __syncthreads();
    for (int k = tid; k < B_TREES * N_NODES; k += 256)
        atomicAdd(&counts[depth[k >> 7][k & 127]], 1);
    __syncthreads();
    if (tid == 0) {
        int acc = 0;
        int nl = 0;
        for (int l = 0; l < MAXL; ++l) {
            base[l] = acc;
            acc += counts[l];
            if (counts[l] > 0) nl = l + 1;
        }
        base[MAXL] = acc;
        level_off[MAXL + 1] = nl;
    }
    __syncthreads();
    for (int k = tid; k <= MAXL; k += 256) level_off[k] = base[k];
    for (int k = tid; k < MAXL; k += 256) counts[k] = 0;
    __syncthreads();
    for (int k = tid; k < B_TREES * N_NODES; k += 256) {
        const int d = depth[k >> 7][k & 127];
        const int pos = base[d] + atomicAdd(&counts[d], 1);
        sched[pos] = k;
    }
}

// Level-parallel tree GRU. 1024 threads = 4 subgroups x 256; each subgroup
// processes TPB=4 nodes with its own LDS panel. Capacity/pass = 4096 nodes.
__global__ __launch_bounds__(1024, 1) void tree_scan_lp(
    const float* __restrict__ P, const uint4* __restrict__ UTb,
    const int* __restrict__ parents,
    const int* __restrict__ sched, const int* __restrict__ level_off,
    float* __restrict__ Ssh, float* __restrict__ Sru) {
    cg::grid_group grid = cg::this_grid();
    const int h = threadIdx.x & 255;
    const int sg = threadIdx.x >> 8;          // 0..3
    const int wg = blockIdx.x;
    __shared__ float hsp_s[NSG][H_DIM][TPB];
    __shared__ float hrp_s[NSG][H_DIM][TPB];
    __shared__ float aux_s[NSG][H_DIM][TPB];
    __shared__ float hsh_s[NSG][H_DIM][TPB];

    const uint4* __restrict__ U0b = UTb + 0 * 8192;
    const uint4* __restrict__ U1b = UTb + 1 * 8192;
    const uint4* __restrict__ U2b = UTb + 2 * 8192;
    const uint4* __restrict__ U3b = UTb + 3 * 8192;
    const uint4* __restrict__ U4b = UTb + 4 * 8192;
    const uint4* __restrict__ U5b = UTb + 5 * 8192;
    const uint4* __restrict__ U6b = UTb + 6 * 8192;
    const uint4* __restrict__ U7b = UTb + 7 * 8192;
    const uint4* __restrict__ U8b = UTb + 8 * 8192;

    const int nlev = level_off[MAXL + 1];
    for (int l = 0; l < nlev; ++l) {
        const int lo = level_off[l], hi = level_off[l + 1];
        // capacity 256 WGs * 4 sg * 4 nodes = 4096 >= any level: single pass
        {
            const int idx0 = lo + (wg * NSG + sg) * TPB;
            int  node[TPB];
            bool val[TPB];
            float phs[TPB], phr[TPB];
#pragma unroll
            for (int t = 0; t < TPB; ++t) {
                const int idx = idx0 + t;
                val[t] = idx < hi;
                const int nd = val[t] ? sched[idx] : sched[lo];
                node[t] = nd;
                const int p = parents[nd];
                float hs = 0.f, hr = 0.f;
                if (p != 0) {
                    const size_t pr = ((size_t)((nd & ~127) + p - 1)) * H_DIM + h;
                    hs = Ssh[pr];
                    hr = Sru[pr];
                }
                phs[t] = hs;
                phr[t] = hr;
            }
            *(float4*)&hsp_s[sg][h][0] = make_float4(phs[0], phs[1], phs[2], phs[3]);
            *(float4*)&hrp_s[sg][h][0] = make_float4(phr[0], phr[1], phr[2], phr[3]);
            __syncthreads();

            // ---------------- stage 1: r_sh, z_sh ----------------
            float pr_[TPB], pz_[TPB];
#pragma unroll
            for (int t = 0; t < TPB; ++t) {
                const float* Pi = P + (size_t)node[t] * 1536;
                pr_[t] = Pi[h];
                pz_[t] = Pi[256 + h];
            }
            float dr[TPB] = {0.f, 0.f, 0.f, 0.f};
            float dz[TPB] = {0.f, 0.f, 0.f, 0.f};
#pragma unroll 4
            for (int jb = 0; jb < 32; ++jb) {
                const uint4 w0 = U0b[jb * 256 + h];
                const uint4 w1 = U1b[jb * 256 + h];
                float a[8], c[8];
                unpack8(w0, a);
                unpack8(w1, c);
#pragma unroll
                for (int q = 0; q < 8; ++q) {
                    const float4 hv = *(const float4*)&hsp_s[sg][jb * 8 + q][0];
                    const float hv4[4] = {hv.x, hv.y, hv.z, hv.w};
#pragma unroll
                    for (int t = 0; t < TPB; ++t) {
                        dr[t] = fmaf(a[q], hv4[t], dr[t]);
                        dz[t] = fmaf(c[q], hv4[t], dz[t]);
                    }
                }
            }
            float z_sh[TPB], vsh[TPB];
#pragma unroll
            for (int t = 0; t < TPB; ++t) {
                const float r_sh = sigmoidf_(pr_[t] + dr[t]);
                z_sh[t] = sigmoidf_(pz_[t] + dz[t]);
                vsh[t] = phs[t] * r_sh;
            }
            *(float4*)&aux_s[sg][h][0] = make_float4(vsh[0], vsh[1], vsh[2], vsh[3]);
            __syncthreads();

            // ---------------- stage 2: h_sh ----------------
            float ph_[TPB];
#pragma unroll
            for (int t = 0; t < TPB; ++t)
                ph_[t] = P[(size_t)node[t] * 1536 + 512 + h];
            float dh[TPB] = {0.f, 0.f, 0.f, 0.f};
#pragma unroll 8
            for (int jb = 0; jb < 32; ++jb) {
                const uint4 w2 = U2b[jb * 256 + h];
                float a[8];
                unpack8(w2, a);
#pragma unroll
                for (int q = 0; q < 8; ++q) {
                    const float4 hv = *(const float4*)&aux_s[sg][jb * 8 + q][0];
                    const float hv4[4] = {hv.x, hv.y, hv.z, hv.w};
#pragma unroll
                    for (int t = 0; t < TPB; ++t)
                        dh[t] = fmaf(a[q], hv4[t], dh[t]);
                }
            }
            float hsh[TPB];
#pragma unroll
            for (int t = 0; t < TPB; ++t) {
                const float hsh_t = tanhf(ph_[t] + dh[t]);
                hsh[t] = (1.f - z_sh[t]) * phs[t] + z_sh[t] * hsh_t;
                if (val[t]) Ssh[(size_t)node[t] * H_DIM + h] = hsh[t];
            }
            *(float4*)&hsh_s[sg][h][0] = make_float4(hsh[0], hsh[1], hsh[2], hsh[3]);
            __syncthreads();

            // ---------------- stage 3: r_ru, z_ru ----------------
            float pru_[TPB], pzu_[TPB];
#pragma unroll
            for (int t = 0; t < TPB; ++t) {
                const float* Pi = P + (size_t)node[t] * 1536;
                pru_[t] = Pi[768 + h];
                pzu_[t] = Pi[1024 + h];
            }
            float er[TPB] = {0.f, 0.f, 0.f, 0.f};
            float ez[TPB] = {0.f, 0.f, 0.f, 0.f};
            float fr[TPB] = {0.f, 0.f, 0.f, 0.f};
            float fz[TPB] = {0.f, 0.f, 0.f, 0.f};
#pragma unroll 2
            for (int jb = 0; jb < 32; ++jb) {
                const uint4 w3 = U3b[jb * 256 + h];
                const uint4 w4 = U4b[jb * 256 + h];
                const uint4 w6 = U6b[jb * 256 + h];
                const uint4 w7 = U7b[jb * 256 + h];
                float a3[8], a4[8], a6[8], a7[8];
                unpack8(w3, a3);
                unpack8(w4, a4);
                unpack8(w6, a6);
                unpack8(w7, a7);
#pragma unroll
                for (int q = 0; q < 8; ++q) {
                    const float4 hr4 = *(const float4*)&hrp_s[sg][jb * 8 + q][0];
                    const float4 hs4 = *(const float4*)&hsh_s[sg][jb * 8 + q][0];
                    const float hrv[4] = {hr4.x, hr4.y, hr4.z, hr4.w};
                    const float hsv[4] = {hs4.x, hs4.y, hs4.z, hs4.w};
#pragma unroll
                    for (int t = 0; t < TPB; ++t) {
                        er[t] = fmaf(a3[q], hrv[t], er[t]);
                        ez[t] = fmaf(a4[q], hrv[t], ez[t]);
                        fr[t] = fmaf(a6[q], hsv[t], fr[t]);
                        fz[t] = fmaf(a7[q], hsv[t], fz[t]);
                    }
                }
            }
            float z_ru[TPB], v2[TPB];
#pragma unroll
            for (int t = 0; t < TPB; ++t) {
                const float r_ru = sigmoidf_(pru_[t] + er[t] + fr[t]);
                z_ru[t] = sigmoidf_(pzu_[t] + ez[t] + fz[t]);
                v2[t] = phr[t] * r_ru;
            }
            *(float4*)&aux_s[sg][h][0] = make_float4(v2[0], v2[1], v2[2], v2[3]);
            __syncthreads();

            // ---------------- stage 4: h_ru ----------------
            float phu_[TPB];
#pragma unroll
            for (int t = 0; t < TPB; ++t)
                phu_[t] = P[(size_t)node[t] * 1536 + 1280 + h];
            float eh[TPB] = {0.f, 0.f, 0.f, 0.f};
            float fh[TPB] = {0.f, 0.f, 0.f, 0.f};
#pragma unroll 4
            for (int jb = 0; jb < 32; ++jb) {
                const uint4 w5 = U5b[jb * 256 + h];
                const uint4 w8 = U8b[jb * 256 + h];
                float a5[8], a8[8];
                unpack8(w5, a5);
                unpack8(w8, a8);
#pragma unroll
                for (int q = 0; q < 8; ++q) {
                    const float4 v4 = *(const float4*)&aux_s[sg][jb * 8 + q][0];
                    const float4 s4 = *(const float4*)&hsh_s[sg][jb * 8 + q][0];
                    const float vv[4] = {v4.x, v4.y, v4.z, v4.w};
                    const float sv[4] = {s4.x, s4.y, s4.z, s4.w};
#pragma unroll
                    for (int t = 0; t < TPB; ++t) {
                        eh[t] = fmaf(a5[q], vv[t], eh[t]);
                        fh[t] = fmaf(a8[q], sv[t], fh[t]);
                    }
                }
            }
#pragma unroll
            for (int t = 0; t < TPB; ++t) {
                const float hru_t = tanhf(phu_[t] + eh[t] + fh[t]);
                const float h_ru = (1.f - z_ru[t]) * phr[t] + z_ru[t] * hru_t;
                if (val[t]) Sru[(size_t)node[t] * H_DIM + h] = h_ru;
            }
            __syncthreads();
        }
        __threadfence();
        grid.sync();
    }
}

__global__ __launch_bounds__(256) void epilogue_k(
    const float* __restrict__ Sru, const int* __restrict__ is_leaf,
    const float* __restrict__ Vr, const float* __restrict__ br,
    float* __restrict__ out) {
    const int b = blockIdx.x;
    const int h = threadIdx.x;
    float m = -3.402823466e38f;
    for (int n = 0; n < N_NODES; ++n) {
        const float v = Sru[((size_t)b * N_NODES + n) * H_DIM + h];
        if (is_leaf[b * N_NODES + n] != 0) m = fmaxf(m, v);
    }
    __shared__ float hm[H_DIM];
    __shared__ float lg[4];
    hm[h] = m;
    __syncthreads();
    if (h < 4) {
        float acc = br[h];
#pragma unroll 8
        for (int j = 0; j < H_DIM; ++j) acc = fmaf(Vr[h * 256 + j], hm[j], acc);
        lg[h] = acc;
    }
    __syncthreads();
    if (h == 0) {
        const float mx = fmaxf(fmaxf(lg[0], lg[1]), fmaxf(lg[2], lg[3]));
        const float e0 = expf(lg[0] - mx);
        const float e1 = expf(lg[1] - mx);
        const float e2 = expf(lg[2] - mx);
        const float e3 = expf(lg[3] - mx);
        const float s = e0 + e1 + e2 + e3;
        out[b * 4 + 0] = e0 / s;
        out[b * 4 + 1] = e1 / s;
        out[b * 4 + 2] = e2 / s;
        out[b * 4 + 3] = e3 / s;
    }
}

extern "C" void kernel_launch(void* const* d_in, const int* in_sizes, int n_in,
                              void* d_out, int out_size, void* d_ws, size_t ws_size,
                              hipStream_t stream) {
    const float* x      = (const float*)d_in[0];
    const float* Er     = (const float*)d_in[1];
    const float* Wsr_r  = (const float*)d_in[2];
    const float* Usr_r  = (const float*)d_in[3];
    const float* Wsr_z  = (const float*)d_in[4];
    const float* Usr_z  = (const float*)d_in[5];
    const float* Wsr_h  = (const float*)d_in[6];
    const float* Usr_h  = (const float*)d_in[7];
    const float* Wr_r   = (const float*)d_in[8];
    const float* Ur_r   = (const float*)d_in[9];
    const float* Usr2r_r= (const float*)d_in[10];
    const float* Wr_z   = (const float*)d_in[11];
    const float* Ur_z   = (const float*)d_in[12];
    const float* Usr2r_z= (const float*)d_in[13];
    const float* Wr_h   = (const float*)d_in[14];
    const float* Ur_h   = (const float*)d_in[15];
    const float* Usr2r_h= (const float*)d_in[16];
    const float* Vr     = (const float*)d_in[17];
    const float* br     = (const float*)d_in[18];
    const int*   parents= (const int*)d_in[19];
    const int*   is_leaf= (const int*)d_in[20];
    float* out = (float*)d_out;

    float* ws = (float*)d_ws;
    float* xt  = ws;                           // 4096*256
    float* P   = xt + 1048576;                 // 4096*1536
    uint4* UTb = (uint4*)(P + 6291456);        // 9*32*256 uint4 (16B aligned)
    float* Ssh = (float*)(UTb + 73728);        // 32*128*256
    float* Sru = Ssh + 1048576;                // 32*128*256
    int*   sched     = (int*)(Sru + 1048576);
    int*   level_off = sched + 4096;

    dim3 blk(256);

    gemm_nt<<<dim3(64, 4), blk, 0, stream>>>(x, Er, xt, 5000, 256);

    const float* Ws[6] = {Wsr_r, Wsr_z, Wsr_h, Wr_r, Wr_z, Wr_h};
    for (int w = 0; w < 6; ++w)
        gemm_nt<<<dim3(64, 4), blk, 0, stream>>>(xt, Ws[w], P + w * 256, 256, 1536);

    transpose_pack_u<<<dim3(32, 9), blk, 0, stream>>>(
        Usr_r, Usr_z, Usr_h, Ur_r, Ur_z, Ur_h, Usr2r_r, Usr2r_z, Usr2r_h, UTb);

    build_schedule<<<dim3(1), blk, 0, stream>>>(parents, sched, level_off);

    void* args[] = {(void*)&P, (void*)&UTb, (void*)&parents,
                    (void*)&sched, (void*)&level_off,
                    (void*)&Ssh, (void*)&Sru};
    (void)hipLaunchCooperativeKernel((const void*)tree_scan_lp,
                                     dim3(GRID_WGS), dim3(1024), args, 0, stream);

    epilogue_k<<<dim3(B_TREES), blk, 0, stream>>>(Sru, is_leaf, Vr, br, out);
}

// Round 7
// 2890.621 us; speedup vs baseline: 1.0476x; 1.0476x over previous
//
#include <hip/hip_runtime.h>
#include <hip/hip_bf16.h>
#include <hip/hip_cooperative_groups.h>
#include <math.h>

namespace cg = cooperative_groups;

// ---------------------------------------------------------------------------
// B=32, N=128, D=5000, H=256, C=4
//   1) x_tilde = x @ Er^T                      (gemm_nt fp32)
//   2) P = x_tilde @ {6 W}^T  (6 gemm_nt launches)
//   3) UTb = bf16-packed transposed U: uint4 = 8 j-values for fixed h
//   4) build_schedule: counting-sort nodes by tree depth
//   5) tree_scan_lp: cooperative 256 WGs x 1024 thr; 4 subgroups/WG (4 waves/
//      SIMD latency hiding). WG-uniform work guard: WG w active iff
//      w*16 < level size (idle WGs go straight to grid.sync -> no dummy
//      streaming of P/U, the R6 regression).
//   6) epilogue
// ---------------------------------------------------------------------------

#define H_DIM 256
#define N_NODES 128
#define B_TREES 32
#define MAXL 128
#define TPB 4
#define NSG 4
#define GRID_WGS 256

__device__ __forceinline__ float sigmoidf_(float x) {
    return 1.0f / (1.0f + expf(-x));
}
__device__ __forceinline__ unsigned bfp(float x) {  // fp32 -> bf16 bits (RNE)
    unsigned u = __float_as_uint(x);
    return (u + 0x7fffu + ((u >> 16) & 1u)) >> 16;
}
__device__ __forceinline__ float bflo(unsigned w) { return __uint_as_float(w << 16); }
__device__ __forceinline__ float bfhi(unsigned w) { return __uint_as_float(w & 0xffff0000u); }

__device__ __forceinline__ void unpack8(uint4 v, float* f) {
    f[0] = bflo(v.x); f[1] = bfhi(v.x);
    f[2] = bflo(v.y); f[3] = bfhi(v.y);
    f[4] = bflo(v.z); f[5] = bfhi(v.z);
    f[6] = bflo(v.w); f[7] = bfhi(v.w);
}

// C[M,N] = A[M,K] @ B[N,K]^T   (row-major, K contiguous; M,N mult of 64)
__global__ __launch_bounds__(256) void gemm_nt(
    const float* __restrict__ A, const float* __restrict__ B,
    float* __restrict__ C, int K, int ldc) {
    __shared__ float As[64][68];
    __shared__ float Bs[64][68];
    const int tid = threadIdx.x;
    const int bm = blockIdx.x, bn = blockIdx.y;
    const int tx = tid & 15, ty = tid >> 4;
    float acc[4][4] = {{0.f}};
    const int nk = (K + 63) >> 6;
    for (int kt = 0; kt < nk; ++kt) {
        const int k0 = kt << 6;
#pragma unroll
        for (int it = 0; it < 4; ++it) {
            const int f = tid + it * 256;
            const int row = f >> 4;
            const int cq = f & 15;
            const int kcol = k0 + cq * 4;
            float4 av = make_float4(0.f, 0.f, 0.f, 0.f);
            float4 bv = make_float4(0.f, 0.f, 0.f, 0.f);
            if (kcol < K) {
                av = *(const float4*)(A + (size_t)(bm * 64 + row) * K + kcol);
                bv = *(const float4*)(B + (size_t)(bn * 64 + row) * K + kcol);
            }
            *(float4*)&As[row][cq * 4] = av;
            *(float4*)&Bs[row][cq * 4] = bv;
        }
        __syncthreads();
#pragma unroll 4
        for (int kk = 0; kk < 64; kk += 4) {
            float4 a[4], bq[4];
#pragma unroll
            for (int i = 0; i < 4; ++i) a[i] = *(const float4*)&As[ty * 4 + i][kk];
#pragma unroll
            for (int j = 0; j < 4; ++j) bq[j] = *(const float4*)&Bs[tx * 4 + j][kk];
#pragma unroll
            for (int i = 0; i < 4; ++i)
#pragma unroll
                for (int j = 0; j < 4; ++j)
                    acc[i][j] += a[i].x * bq[j].x + a[i].y * bq[j].y +
                                 a[i].z * bq[j].z + a[i].w * bq[j].w;
        }
        __syncthreads();
    }
#pragma unroll
    for (int i = 0; i < 4; ++i) {
        float4 o = make_float4(acc[i][0], acc[i][1], acc[i][2], acc[i][3]);
        *(float4*)(C + (size_t)(bm * 64 + ty * 4 + i) * ldc + bn * 64 + tx * 4) = o;
    }
}

// UTb[(m*32 + jblk)*256 + h] = uint4 of 8 bf16 = U_m[h][8*jblk .. 8*jblk+7]
__global__ __launch_bounds__(256) void transpose_pack_u(
    const float* __restrict__ U0, const float* __restrict__ U1,
    const float* __restrict__ U2, const float* __restrict__ U3,
    const float* __restrict__ U4, const float* __restrict__ U5,
    const float* __restrict__ U6, const float* __restrict__ U7,
    const float* __restrict__ U8, uint4* __restrict__ UTb) {
    const float* Us[9] = {U0, U1, U2, U3, U4, U5, U6, U7, U8};
    const int jb = blockIdx.x;     // 0..31
    const int m = blockIdx.y;      // 0..8
    const int h = threadIdx.x;     // 0..255
    const float* U = Us[m] + (size_t)h * 256 + jb * 8;
    uint4 v;
    v.x = bfp(U[0]) | (bfp(U[1]) << 16);
    v.y = bfp(U[2]) | (bfp(U[3]) << 16);
    v.z = bfp(U[4]) | (bfp(U[5]) << 16);
    v.w = bfp(U[6]) | (bfp(U[7]) << 16);
    UTb[(size_t)(m * 32 + jb) * 256 + h] = v;
}

__global__ __launch_bounds__(256) void build_schedule(
    const int* __restrict__ parents, int* __restrict__ sched,
    int* __restrict__ level_off) {
    __shared__ unsigned char depth[B_TREES][N_NODES];
    __shared__ int counts[MAXL];
    __shared__ int base[MAXL + 1];
    const int tid = threadIdx.x;
    for (int k = tid; k < MAXL; k += 256) counts[k] = 0;
    __syncthreads();
    if (tid < B_TREES) {
        depth[tid][0] = 0;
        for (int i = 1; i < N_NODES; ++i) {
            const int p = parents[tid * N_NODES + i];
            depth[tid][i] = (unsigned char)(depth[tid][p - 1] + 1);
        }
    }
    __syncthreads();
    for (int k = tid; k < B_TREES * N_NODES; k += 256)
        atomicAdd(&counts[depth[k >> 7][k & 127]], 1);
    __syncthreads();
    if (tid == 0) {
        int acc = 0;
        int nl = 0;
        for (int l = 0; l < MAXL; ++l) {
            base[l] = acc;
            acc += counts[l];
            if (counts[l] > 0) nl = l + 1;
        }
        base[MAXL] = acc;
        level_off[MAXL + 1] = nl;
    }
    __syncthreads();
    for (int k = tid; k <= MAXL; k += 256) level_off[k] = base[k];
    for (int k = tid; k < MAXL; k += 256) counts[k] = 0;
    __syncthreads();
    for (int k = tid; k < B_TREES * N_NODES; k += 256) {
        const int d = depth[k >> 7][k & 127];
        const int pos = base[d] + atomicAdd(&counts[d], 1);
        sched[pos] = k;
    }
}

// Level-parallel tree GRU. 1024 threads = 4 subgroups x 256; each subgroup
// processes TPB=4 nodes with its own LDS panel. WG-uniform work guard keeps
// idle WGs off the P/U streams (R6 lesson) while active CUs get 4 waves/SIMD.
__global__ __launch_bounds__(1024, 1) void tree_scan_lp(
    const float* __restrict__ P, const uint4* __restrict__ UTb,
    const int* __restrict__ parents,
    const int* __restrict__ sched, const int* __restrict__ level_off,
    float* __restrict__ Ssh, float* __restrict__ Sru) {
    cg::grid_group grid = cg::this_grid();
    const int h = threadIdx.x & 255;
    const int sg = threadIdx.x >> 8;          // 0..3
    const int wg = blockIdx.x;
    __shared__ float hsp_s[NSG][H_DIM][TPB];
    __shared__ float hrp_s[NSG][H_DIM][TPB];
    __shared__ float aux_s[NSG][H_DIM][TPB];
    __shared__ float hsh_s[NSG][H_DIM][TPB];

    const uint4* __restrict__ U0b = UTb + 0 * 8192;
    const uint4* __restrict__ U1b = UTb + 1 * 8192;
    const uint4* __restrict__ U2b = UTb + 2 * 8192;
    const uint4* __restrict__ U3b = UTb + 3 * 8192;
    const uint4* __restrict__ U4b = UTb + 4 * 8192;
    const uint4* __restrict__ U5b = UTb + 5 * 8192;
    const uint4* __restrict__ U6b = UTb + 6 * 8192;
    const uint4* __restrict__ U7b = UTb + 7 * 8192;
    const uint4* __restrict__ U8b = UTb + 8 * 8192;

    const int nlev = level_off[MAXL + 1];
    for (int l = 0; l < nlev; ++l) {
        const int lo = level_off[l], hi = level_off[l + 1];
        // WG-uniform guard: only WGs with assigned nodes run the body.
        if (wg * (NSG * TPB) < hi - lo) {
            const int idx0 = lo + (wg * NSG + sg) * TPB;
            int  node[TPB];
            bool val[TPB];
            float phs[TPB], phr[TPB];
#pragma unroll
            for (int t = 0; t < TPB; ++t) {
                const int idx = idx0 + t;
                val[t] = idx < hi;
                const int nd = val[t] ? sched[idx] : sched[lo];
                node[t] = nd;
                const int p = parents[nd];
                float hs = 0.f, hr = 0.f;
                if (p != 0) {
                    const size_t pr = ((size_t)((nd & ~127) + p - 1)) * H_DIM + h;
                    hs = Ssh[pr];
                    hr = Sru[pr];
                }
                phs[t] = hs;
                phr[t] = hr;
            }
            *(float4*)&hsp_s[sg][h][0] = make_float4(phs[0], phs[1], phs[2], phs[3]);
            *(float4*)&hrp_s[sg][h][0] = make_float4(phr[0], phr[1], phr[2], phr[3]);
            __syncthreads();

            // ---------------- stage 1: r_sh, z_sh ----------------
            float pr_[TPB], pz_[TPB];
#pragma unroll
            for (int t = 0; t < TPB; ++t) {
                const float* Pi = P + (size_t)node[t] * 1536;
                pr_[t] = Pi[h];
                pz_[t] = Pi[256 + h];
            }
            float dr[TPB] = {0.f, 0.f, 0.f, 0.f};
            float dz[TPB] = {0.f, 0.f, 0.f, 0.f};
#pragma unroll 4
            for (int jb = 0; jb < 32; ++jb) {
                const uint4 w0 = U0b[jb * 256 + h];
                const uint4 w1 = U1b[jb * 256 + h];
                float a[8], c[8];
                unpack8(w0, a);
                unpack8(w1, c);
#pragma unroll
                for (int q = 0; q < 8; ++q) {
                    const float4 hv = *(const float4*)&hsp_s[sg][jb * 8 + q][0];
                    const float hv4[4] = {hv.x, hv.y, hv.z, hv.w};
#pragma unroll
                    for (int t = 0; t < TPB; ++t) {
                        dr[t] = fmaf(a[q], hv4[t], dr[t]);
                        dz[t] = fmaf(c[q], hv4[t], dz[t]);
                    }
                }
            }
            float z_sh[TPB], vsh[TPB];
#pragma unroll
            for (int t = 0; t < TPB; ++t) {
                const float r_sh = sigmoidf_(pr_[t] + dr[t]);
                z_sh[t] = sigmoidf_(pz_[t] + dz[t]);
                vsh[t] = phs[t] * r_sh;
            }
            *(float4*)&aux_s[sg][h][0] = make_float4(vsh[0], vsh[1], vsh[2], vsh[3]);
            __syncthreads();

            // ---------------- stage 2: h_sh ----------------
            float ph_[TPB];
#pragma unroll
            for (int t = 0; t < TPB; ++t)
                ph_[t] = P[(size_t)node[t] * 1536 + 512 + h];
            float dh[TPB] = {0.f, 0.f, 0.f, 0.f};
#pragma unroll 8
            for (int jb = 0; jb < 32; ++jb) {
                const uint4 w2 = U2b[jb * 256 + h];
                float a[8];
                unpack8(w2, a);
#pragma unroll
                for (int q = 0; q < 8; ++q) {
                    const float4 hv = *(const float4*)&aux_s[sg][jb * 8 + q][0];
                    const float hv4[4] = {hv.x, hv.y, hv.z, hv.w};
#pragma unroll
                    for (int t = 0; t < TPB; ++t)
                        dh[t] = fmaf(a[q], hv4[t], dh[t]);
                }
            }
            float hsh[TPB];
#pragma unroll
            for (int t = 0; t < TPB; ++t) {
                const float hsh_t = tanhf(ph_[t] + dh[t]);
                hsh[t] = (1.f - z_sh[t]) * phs[t] + z_sh[t] * hsh_t;
                if (val[t]) Ssh[(size_t)node[t] * H_DIM + h] = hsh[t];
            }
            *(float4*)&hsh_s[sg][h][0] = make_float4(hsh[0], hsh[1], hsh[2], hsh[3]);
            __syncthreads();

            // ---------------- stage 3: r_ru, z_ru ----------------
            float pru_[TPB], pzu_[TPB];
#pragma unroll
            for (int t = 0; t < TPB; ++t) {
                const float* Pi = P + (size_t)node[t] * 1536;
                pru_[t] = Pi[768 + h];
                pzu_[t] = Pi[1024 + h];
            }
            float er[TPB] = {0.f, 0.f, 0.f, 0.f};
            float ez[TPB] = {0.f, 0.f, 0.f, 0.f};
            float fr[TPB] = {0.f, 0.f, 0.f, 0.f};
            float fz[TPB] = {0.f, 0.f, 0.f, 0.f};
#pragma unroll 2
            for (int jb = 0; jb < 32; ++jb) {
                const uint4 w3 = U3b[jb * 256 + h];
                const uint4 w4 = U4b[jb * 256 + h];
                const uint4 w6 = U6b[jb * 256 + h];
                const uint4 w7 = U7b[jb * 256 + h];
                float a3[8], a4[8], a6[8], a7[8];
                unpack8(w3, a3);
                unpack8(w4, a4);
                unpack8(w6, a6);
                unpack8(w7, a7);
#pragma unroll
                for (int q = 0; q < 8; ++q) {
                    const float4 hr4 = *(const float4*)&hrp_s[sg][jb * 8 + q][0];
                    const float4 hs4 = *(const float4*)&hsh_s[sg][jb * 8 + q][0];
                    const float hrv[4] = {hr4.x, hr4.y, hr4.z, hr4.w};
                    const float hsv[4] = {hs4.x, hs4.y, hs4.z, hs4.w};
#pragma unroll
                    for (int t = 0; t < TPB; ++t) {
                        er[t] = fmaf(a3[q], hrv[t], er[t]);
                        ez[t] = fmaf(a4[q], hrv[t], ez[t]);
                        fr[t] = fmaf(a6[q], hsv[t], fr[t]);
                        fz[t] = fmaf(a7[q], hsv[t], fz[t]);
                    }
                }
            }
            float z_ru[TPB], v2[TPB];
#pragma unroll
            for (int t = 0; t < TPB; ++t) {
                const float r_ru = sigmoidf_(pru_[t] + er[t] + fr[t]);
                z_ru[t] = sigmoidf_(pzu_[t] + ez[t] + fz[t]);
                v2[t] = phr[t] * r_ru;
            }
            *(float4*)&aux_s[sg][h][0] = make_float4(v2[0], v2[1], v2[2], v2[3]);
            __syncthreads();

            // ---------------- stage 4: h_ru ----------------
            float phu_[TPB];
#pragma unroll
            for (int t = 0; t < TPB; ++t)
                phu_[t] = P[(size_t)node[t] * 1536 + 1280 + h];
            float eh[TPB] = {0.f, 0.f, 0.f, 0.f};
            float fh[TPB] = {0.f, 0.f, 0.f, 0.f};
#pragma unroll 4
            for (int jb = 0; jb < 32; ++jb) {
                const uint4 w5 = U5b[jb * 256 + h];
                const uint4 w8 = U8b[jb * 256 + h];
                float a5[8], a8[8];
                unpack8(w5, a5);
                unpack8(w8, a8);
#pragma unroll
                for (int q = 0; q < 8; ++q) {
                    const float4 v4 = *(const float4*)&aux_s[sg][jb * 8 + q][0];
                    const float4 s4 = *(const float4*)&hsh_s[sg][jb * 8 + q][0];
                    const float vv[4] = {v4.x, v4.y, v4.z, v4.w};
                    const float sv[4] = {s4.x, s4.y, s4.z, s4.w};
#pragma unroll
                    for (int t = 0; t < TPB; ++t) {
                        eh[t] = fmaf(a5[q], vv[t], eh[t]);
                        fh[t] = fmaf(a8[q], sv[t], fh[t]);
                    }
                }
            }
#pragma unroll
            for (int t = 0; t < TPB; ++t) {
                const float hru_t = tanhf(phu_[t] + eh[t] + fh[t]);
                const float h_ru = (1.f - z_ru[t]) * phr[t] + z_ru[t] * hru_t;
                if (val[t]) Sru[(size_t)node[t] * H_DIM + h] = h_ru;
            }
            __syncthreads();
        }
        __threadfence();
        grid.sync();
    }
}

__global__ __launch_bounds__(256) void epilogue_k(
    const float* __restrict__ Sru, const int* __restrict__ is_leaf,
    const float* __restrict__ Vr, const float* __restrict__ br,
    float* __restrict__ out) {
    const int b = blockIdx.x;
    const int h = threadIdx.x;
    float m = -3.402823466e38f;
    for (int n = 0; n < N_NODES; ++n) {
        const float v = Sru[((size_t)b * N_NODES + n) * H_DIM + h];
        if (is_leaf[b * N_NODES + n] != 0) m = fmaxf(m, v);
    }
    __shared__ float hm[H_DIM];
    __shared__ float lg[4];
    hm[h] = m;
    __syncthreads();
    if (h < 4) {
        float acc = br[h];
#pragma unroll 8
        for (int j = 0; j < H_DIM; ++j) acc = fmaf(Vr[h * 256 + j], hm[j], acc);
        lg[h] = acc;
    }
    __syncthreads();
    if (h == 0) {
        const float mx = fmaxf(fmaxf(lg[0], lg[1]), fmaxf(lg[2], lg[3]));
        const float e0 = expf(lg[0] - mx);
        const float e1 = expf(lg[1] - mx);
        const float e2 = expf(lg[2] - mx);
        const float e3 = expf(lg[3] - mx);
        const float s = e0 + e1 + e2 + e3;
        out[b * 4 + 0] = e0 / s;
        out[b * 4 + 1] = e1 / s;
        out[b * 4 + 2] = e2 / s;
        out[b * 4 + 3] = e3 / s;
    }
}

extern "C" void kernel_launch(void* const* d_in, const int* in_sizes, int n_in,
                              void* d_out, int out_size, void* d_ws, size_t ws_size,
                              hipStream_t stream) {
    const float* x      = (const float*)d_in[0];
    const float* Er     = (const float*)d_in[1];
    const float* Wsr_r  = (const float*)d_in[2];
    const float* Usr_r  = (const float*)d_in[3];
    const float* Wsr_z  = (const float*)d_in[4];
    const float* Usr_z  = (const float*)d_in[5];
    const float* Wsr_h  = (const float*)d_in[6];
    const float* Usr_h  = (const float*)d_in[7];
    const float* Wr_r   = (const float*)d_in[8];
    const float* Ur_r   = (const float*)d_in[9];
    const float* Usr2r_r= (const float*)d_in[10];
    const float* Wr_z   = (const float*)d_in[11];
    const float* Ur_z   = (const float*)d_in[12];
    const float* Usr2r_z= (const float*)d_in[13];
    const float* Wr_h   = (const float*)d_in[14];
    const float* Ur_h   = (const float*)d_in[15];
    const float* Usr2r_h= (const float*)d_in[16];
    const float* Vr     = (const float*)d_in[17];
    const float* br     = (const float*)d_in[18];
    const int*   parents= (const int*)d_in[19];
    const int*   is_leaf= (const int*)d_in[20];
    float* out = (float*)d_out;

    float* ws = (float*)d_ws;
    float* xt  = ws;                           // 4096*256
    float* P   = xt + 1048576;                 // 4096*1536
    uint4* UTb = (uint4*)(P + 6291456);        // 9*32*256 uint4 (16B aligned)
    float* Ssh = (float*)(UTb + 73728);        // 32*128*256
    float* Sru = Ssh + 1048576;                // 32*128*256
    int*   sched     = (int*)(Sru + 1048576);
    int*   level_off = sched + 4096;

    dim3 blk(256);

    gemm_nt<<<dim3(64, 4), blk, 0, stream>>>(x, Er, xt, 5000, 256);

    const float* Ws[6] = {Wsr_r, Wsr_z, Wsr_h, Wr_r, Wr_z, Wr_h};
    for (int w = 0; w < 6; ++w)
        gemm_nt<<<dim3(64, 4), blk, 0, stream>>>(xt, Ws[w], P + w * 256, 256, 1536);

    transpose_pack_u<<<dim3(32, 9), blk, 0, stream>>>(
        Usr_r, Usr_z, Usr_h, Ur_r, Ur_z, Ur_h, Usr2r_r, Usr2r_z, Usr2r_h, UTb);

    build_schedule<<<dim3(1), blk, 0, stream>>>(parents, sched, level_off);

    void* args[] = {(void*)&P, (void*)&UTb, (void*)&parents,
                    (void*)&sched, (void*)&level_off,
                    (void*)&Ssh, (void*)&Sru};
    (void)hipLaunchCooperativeKernel((const void*)tree_scan_lp,
                                     dim3(GRID_WGS), dim3(1024), args, 0, stream);

    epilogue_k<<<dim3(B_TREES), blk, 0, stream>>>(Sru, is_leaf, Vr, br, out);
}

// Round 8
// 1601.092 us; speedup vs baseline: 1.8914x; 1.8054x over previous
//
#include <hip/hip_runtime.h>
#include <hip/hip_bf16.h>
#include <hip/hip_cooperative_groups.h>
#include <math.h>

namespace cg = cooperative_groups;

// ---------------------------------------------------------------------------
// B=32, N=128, D=5000, H=256, C=4
//   1) x_tilde = x @ Er^T            (MFMA bf16 NT gemm, fp32 in/out)
//   2) Wcat = concat 6 W (d2d memcpy); P = x_tilde @ Wcat^T (one MFMA gemm)
//   3) UTb = bf16-packed transposed U
//   4) build_schedule
//   5) tree_scan_lp: R5-EXACT (256 WGs x 256 thr, TPB=4) — spread-wide wins
//      for latency-bound bodies (R6/R7 lesson: stacking subgroups regressed)
//   6) epilogue
// ---------------------------------------------------------------------------

#define H_DIM 256
#define N_NODES 128
#define B_TREES 32
#define MAXL 128
#define TPB 4
#define GRID_WGS 256

typedef short bf16x8 __attribute__((ext_vector_type(8)));
typedef float f32x4 __attribute__((ext_vector_type(4)));

__device__ __forceinline__ float sigmoidf_(float x) {
    return 1.0f / (1.0f + expf(-x));
}
__device__ __forceinline__ unsigned bfp(float x) {  // fp32 -> bf16 bits (RNE)
    unsigned u = __float_as_uint(x);
    return (u + 0x7fffu + ((u >> 16) & 1u)) >> 16;
}
__device__ __forceinline__ float bflo(unsigned w) { return __uint_as_float(w << 16); }
__device__ __forceinline__ float bfhi(unsigned w) { return __uint_as_float(w & 0xffff0000u); }

__device__ __forceinline__ void unpack8(uint4 v, float* f) {
    f[0] = bflo(v.x); f[1] = bfhi(v.x);
    f[2] = bflo(v.y); f[3] = bfhi(v.y);
    f[4] = bflo(v.z); f[5] = bfhi(v.z);
    f[6] = bflo(v.w); f[7] = bfhi(v.w);
}

// ---------------------------------------------------------------------------
// MFMA bf16 NT GEMM: C[M,N] = A[M,K] @ B[N,K]^T, fp32 in/out, bf16 compute.
// 64x64 tile, 256 thr (4 waves); wave w owns rows w*16..w*16+15, all 64 cols.
// LDS rows padded to 40 shorts (80B) to avoid 8-way bank conflicts.
// Fragment maps (verified, learn_hip m89/m120): A[m=lane&15][k=(lane>>4)*8+j];
// C/D: row=(lane>>4)*4+reg, col=lane&15.
// ---------------------------------------------------------------------------
__global__ __launch_bounds__(256) void gemm_mfma_nt(
    const float* __restrict__ A, const float* __restrict__ B,
    float* __restrict__ C, int K, int ldc) {
    __shared__ short As[64][40];
    __shared__ short Bs[64][40];
    const int tid = threadIdx.x;
    const int bm = blockIdx.x, bn = blockIdx.y;
    const int row = tid >> 2;          // 0..63 staging row
    const int quad = tid & 3;          // 0..3  staging k-quad (8 elems)
    const int wave = tid >> 6;         // 0..3
    const int lane = tid & 63;
    const int lm = lane & 15;          // fragment row
    const int kq = lane >> 4;          // 0..3

    f32x4 acc[4];
#pragma unroll
    for (int i = 0; i < 4; ++i) acc[i] = (f32x4){0.f, 0.f, 0.f, 0.f};

    const int nk = (K + 31) >> 5;
    for (int kt = 0; kt < nk; ++kt) {
        const int k0 = kt << 5;
        const int kbase = k0 + quad * 8;
        // ---- stage A row ----
        {
            float a8[8];
            const float* Ap = A + (size_t)(bm * 64 + row) * K + kbase;
            if (kbase + 8 <= K) {
                const float4 v0 = *(const float4*)Ap;
                const float4 v1 = *(const float4*)(Ap + 4);
                a8[0] = v0.x; a8[1] = v0.y; a8[2] = v0.z; a8[3] = v0.w;
                a8[4] = v1.x; a8[5] = v1.y; a8[6] = v1.z; a8[7] = v1.w;
            } else {
#pragma unroll
                for (int i = 0; i < 8; ++i)
                    a8[i] = (kbase + i < K) ? Ap[i] : 0.f;
            }
            uint4 v;
            v.x = bfp(a8[0]) | (bfp(a8[1]) << 16);
            v.y = bfp(a8[2]) | (bfp(a8[3]) << 16);
            v.z = bfp(a8[4]) | (bfp(a8[5]) << 16);
            v.w = bfp(a8[6]) | (bfp(a8[7]) << 16);
            *(uint4*)&As[row][quad * 8] = v;
        }
        // ---- stage B row ----
        {
            float b8[8];
            const float* Bp = B + (size_t)(bn * 64 + row) * K + kbase;
            if (kbase + 8 <= K) {
                const float4 v0 = *(const float4*)Bp;
                const float4 v1 = *(const float4*)(Bp + 4);
                b8[0] = v0.x; b8[1] = v0.y; b8[2] = v0.z; b8[3] = v0.w;
                b8[4] = v1.x; b8[5] = v1.y; b8[6] = v1.z; b8[7] = v1.w;
            } else {
#pragma unroll
                for (int i = 0; i < 8; ++i)
                    b8[i] = (kbase + i < K) ? Bp[i] : 0.f;
            }
            uint4 v;
            v.x = bfp(b8[0]) | (bfp(b8[1]) << 16);
            v.y = bfp(b8[2]) | (bfp(b8[3]) << 16);
            v.z = bfp(b8[4]) | (bfp(b8[5]) << 16);
            v.w = bfp(b8[6]) | (bfp(b8[7]) << 16);
            *(uint4*)&Bs[row][quad * 8] = v;
        }
        __syncthreads();
        // ---- MFMA: one 16x16x32 per n-tile ----
        const bf16x8 af = *(const bf16x8*)&As[wave * 16 + lm][kq * 8];
#pragma unroll
        for (int nt = 0; nt < 4; ++nt) {
            const bf16x8 bf = *(const bf16x8*)&Bs[nt * 16 + lm][kq * 8];
            acc[nt] = __builtin_amdgcn_mfma_f32_16x16x32_bf16(af, bf, acc[nt], 0, 0, 0);
        }
        __syncthreads();
    }
    // ---- epilogue: C[row=(lane>>4)*4+r, col=lane&15] ----
#pragma unroll
    for (int nt = 0; nt < 4; ++nt) {
#pragma unroll
        for (int r = 0; r < 4; ++r) {
            const int gm = bm * 64 + wave * 16 + kq * 4 + r;
            const int gn = bn * 64 + nt * 16 + lm;
            C[(size_t)gm * ldc + gn] = acc[nt][r];
        }
    }
}

// UTb[(m*32 + jblk)*256 + h] = uint4 of 8 bf16 = U_m[h][8*jblk .. 8*jblk+7]
__global__ __launch_bounds__(256) void transpose_pack_u(
    const float* __restrict__ U0, const float* __restrict__ U1,
    const float* __restrict__ U2, const float* __restrict__ U3,
    const float* __restrict__ U4, const float* __restrict__ U5,
    const float* __restrict__ U6, const float* __restrict__ U7,
    const float* __restrict__ U8, uint4* __restrict__ UTb) {
    const float* Us[9] = {U0, U1, U2, U3, U4, U5, U6, U7, U8};
    const int jb = blockIdx.x;     // 0..31
    const int m = blockIdx.y;      // 0..8
    const int h = threadIdx.x;     // 0..255
    const float* U = Us[m] + (size_t)h * 256 + jb * 8;
    uint4 v;
    v.x = bfp(U[0]) | (bfp(U[1]) << 16);
    v.y = bfp(U[2]) | (bfp(U[3]) << 16);
    v.z = bfp(U[4]) | (bfp(U[5]) << 16);
    v.w = bfp(U[6]) | (bfp(U[7]) << 16);
    UTb[(size_t)(m * 32 + jb) * 256 + h] = v;
}

__global__ __launch_bounds__(256) void build_schedule(
    const int* __restrict__ parents, int* __restrict__ sched,
    int* __restrict__ level_off) {
    __shared__ unsigned char depth[B_TREES][N_NODES];
    __shared__ int counts[MAXL];
    __shared__ int base[MAXL + 1];
    const int tid = threadIdx.x;
    for (int k = tid; k < MAXL; k += 256) counts[k] = 0;
    __syncthreads();
    if (tid < B_TREES) {
        depth[tid][0] = 0;
        for (int i = 1; i < N_NODES; ++i) {
            const int p = parents[tid * N_NODES + i];
            depth[tid][i] = (unsigned char)(depth[tid][p - 1] + 1);
        }
    }
    __syncthreads();
    for (int k = tid; k < B_TREES * N_NODES; k += 256)
        atomicAdd(&counts[depth[k >> 7][k & 127]], 1);
    __syncthreads();
    if (tid == 0) {
        int acc = 0;
        int nl = 0;
        for (int l = 0; l < MAXL; ++l) {
            base[l] = acc;
            acc += counts[l];
            if (counts[l] > 0) nl = l + 1;
        }
        base[MAXL] = acc;
        level_off[MAXL + 1] = nl;
    }
    __syncthreads();
    for (int k = tid; k <= MAXL; k += 256) level_off[k] = base[k];
    for (int k = tid; k < MAXL; k += 256) counts[k] = 0;
    __syncthreads();
    for (int k = tid; k < B_TREES * N_NODES; k += 256) {
        const int d = depth[k >> 7][k & 127];
        const int pos = base[d] + atomicAdd(&counts[d], 1);
        sched[pos] = k;
    }
}

// Level-parallel tree GRU — R5-EXACT (proven 1178 us).
__global__ __launch_bounds__(256, 1) void tree_scan_lp(
    const float* __restrict__ P, const uint4* __restrict__ UTb,
    const int* __restrict__ parents,
    const int* __restrict__ sched, const int* __restrict__ level_off,
    float* __restrict__ Ssh, float* __restrict__ Sru) {
    cg::grid_group grid = cg::this_grid();
    const int h = threadIdx.x;
    const int wg = blockIdx.x;
    __shared__ float hsp_s[H_DIM][TPB];
    __shared__ float hrp_s[H_DIM][TPB];
    __shared__ float aux_s[H_DIM][TPB];
    __shared__ float hsh_s[H_DIM][TPB];

    const uint4* __restrict__ U0b = UTb + 0 * 8192;
    const uint4* __restrict__ U1b = UTb + 1 * 8192;
    const uint4* __restrict__ U2b = UTb + 2 * 8192;
    const uint4* __restrict__ U3b = UTb + 3 * 8192;
    const uint4* __restrict__ U4b = UTb + 4 * 8192;
    const uint4* __restrict__ U5b = UTb + 5 * 8192;
    const uint4* __restrict__ U6b = UTb + 6 * 8192;
    const uint4* __restrict__ U7b = UTb + 7 * 8192;
    const uint4* __restrict__ U8b = UTb + 8 * 8192;

    const int nlev = level_off[MAXL + 1];
    for (int l = 0; l < nlev; ++l) {
        const int lo = level_off[l], hi = level_off[l + 1];
        for (int b0 = lo + wg * TPB; b0 < hi; b0 += GRID_WGS * TPB) {
            int  node[TPB];
            bool val[TPB];
            float phs[TPB], phr[TPB];
#pragma unroll
            for (int t = 0; t < TPB; ++t) {
                const int idx = b0 + t;
                val[t] = idx < hi;
                const int nd = val[t] ? sched[idx] : sched[b0];
                node[t] = nd;
                const int p = parents[nd];
                float hs = 0.f, hr = 0.f;
                if (p != 0) {
                    const size_t pr = ((size_t)((nd & ~127) + p - 1)) * H_DIM + h;
                    hs = Ssh[pr];
                    hr = Sru[pr];
                }
                phs[t] = hs;
                phr[t] = hr;
            }
            *(float4*)&hsp_s[h][0] = make_float4(phs[0], phs[1], phs[2], phs[3]);
            *(float4*)&hrp_s[h][0] = make_float4(phr[0], phr[1], phr[2], phr[3]);
            __syncthreads();

            // ---------------- stage 1: r_sh, z_sh ----------------
            float pr_[TPB], pz_[TPB];
#pragma unroll
            for (int t = 0; t < TPB; ++t) {
                const float* Pi = P + (size_t)node[t] * 1536;
                pr_[t] = Pi[h];
                pz_[t] = Pi[256 + h];
            }
            float dr[TPB] = {0.f, 0.f, 0.f, 0.f};
            float dz[TPB] = {0.f, 0.f, 0.f, 0.f};
#pragma unroll 4
            for (int jb = 0; jb < 32; ++jb) {
                const uint4 w0 = U0b[jb * 256 + h];
                const uint4 w1 = U1b[jb * 256 + h];
                float a[8], c[8];
                unpack8(w0, a);
                unpack8(w1, c);
#pragma unroll
                for (int q = 0; q < 8; ++q) {
                    const float4 hv = *(const float4*)&hsp_s[jb * 8 + q][0];
                    const float hv4[4] = {hv.x, hv.y, hv.z, hv.w};
#pragma unroll
                    for (int t = 0; t < TPB; ++t) {
                        dr[t] = fmaf(a[q], hv4[t], dr[t]);
                        dz[t] = fmaf(c[q], hv4[t], dz[t]);
                    }
                }
            }
            float z_sh[TPB], vsh[TPB];
#pragma unroll
            for (int t = 0; t < TPB; ++t) {
                const float r_sh = sigmoidf_(pr_[t] + dr[t]);
                z_sh[t] = sigmoidf_(pz_[t] + dz[t]);
                vsh[t] = phs[t] * r_sh;
            }
            *(float4*)&aux_s[h][0] = make_float4(vsh[0], vsh[1], vsh[2], vsh[3]);
            __syncthreads();

            // ---------------- stage 2: h_sh ----------------
            float ph_[TPB];
#pragma unroll
            for (int t = 0; t < TPB; ++t)
                ph_[t] = P[(size_t)node[t] * 1536 + 512 + h];
            float dh[TPB] = {0.f, 0.f, 0.f, 0.f};
#pragma unroll 8
            for (int jb = 0; jb < 32; ++jb) {
                const uint4 w2 = U2b[jb * 256 + h];
                float a[8];
                unpack8(w2, a);
#pragma unroll
                for (int q = 0; q < 8; ++q) {
                    const float4 hv = *(const float4*)&aux_s[jb * 8 + q][0];
                    const float hv4[4] = {hv.x, hv.y, hv.z, hv.w};
#pragma unroll
                    for (int t = 0; t < TPB; ++t)
                        dh[t] = fmaf(a[q], hv4[t], dh[t]);
                }
            }
            float hsh[TPB];
#pragma unroll
            for (int t = 0; t < TPB; ++t) {
                const float hsh_t = tanhf(ph_[t] + dh[t]);
                hsh[t] = (1.f - z_sh[t]) * phs[t] + z_sh[t] * hsh_t;
                if (val[t]) Ssh[(size_t)node[t] * H_DIM + h] = hsh[t];
            }
            *(float4*)&hsh_s[h][0] = make_float4(hsh[0], hsh[1], hsh[2], hsh[3]);
            __syncthreads();

            // ---------------- stage 3: r_ru, z_ru ----------------
            float pru_[TPB], pzu_[TPB];
#pragma unroll
            for (int t = 0; t < TPB; ++t) {
                const float* Pi = P + (size_t)node[t] * 1536;
                pru_[t] = Pi[768 + h];
                pzu_[t] = Pi[1024 + h];
            }
            float er[TPB] = {0.f, 0.f, 0.f, 0.f};
            float ez[TPB] = {0.f, 0.f, 0.f, 0.f};
            float fr[TPB] = {0.f, 0.f, 0.f, 0.f};
            float fz[TPB] = {0.f, 0.f, 0.f, 0.f};
#pragma unroll 2
            for (int jb = 0; jb < 32; ++jb) {
                const uint4 w3 = U3b[jb * 256 + h];
                const uint4 w4 = U4b[jb * 256 + h];
                const uint4 w6 = U6b[jb * 256 + h];
                const uint4 w7 = U7b[jb * 256 + h];
                float a3[8], a4[8], a6[8], a7[8];
                unpack8(w3, a3);
                unpack8(w4, a4);
                unpack8(w6, a6);
                unpack8(w7, a7);
#pragma unroll
                for (int q = 0; q < 8; ++q) {
                    const float4 hr4 = *(const float4*)&hrp_s[jb * 8 + q][0];
                    const float4 hs4 = *(const float4*)&hsh_s[jb * 8 + q][0];
                    const float hrv[4] = {hr4.x, hr4.y, hr4.z, hr4.w};
                    const float hsv[4] = {hs4.x, hs4.y, hs4.z, hs4.w};
#pragma unroll
                    for (int t = 0; t < TPB; ++t) {
                        er[t] = fmaf(a3[q], hrv[t], er[t]);
                        ez[t] = fmaf(a4[q], hrv[t], ez[t]);
                        fr[t] = fmaf(a6[q], hsv[t], fr[t]);
                        fz[t] = fmaf(a7[q], hsv[t], fz[t]);
                    }
                }
            }
            float z_ru[TPB], v2[TPB];
#pragma unroll
            for (int t = 0; t < TPB; ++t) {
                const float r_ru = sigmoidf_(pru_[t] + er[t] + fr[t]);
                z_ru[t] = sigmoidf_(pzu_[t] + ez[t] + fz[t]);
                v2[t] = phr[t] * r_ru;
            }
            *(float4*)&aux_s[h][0] = make_float4(v2[0], v2[1], v2[2], v2[3]);
            __syncthreads();

            // ---------------- stage 4: h_ru ----------------
            float phu_[TPB];
#pragma unroll
            for (int t = 0; t < TPB; ++t)
                phu_[t] = P[(size_t)node[t] * 1536 + 1280 + h];
            float eh[TPB] = {0.f, 0.f, 0.f, 0.f};
            float fh[TPB] = {0.f, 0.f, 0.f, 0.f};
#pragma unroll 4
            for (int jb = 0; jb < 32; ++jb) {
                const uint4 w5 = U5b[jb * 256 + h];
                const uint4 w8 = U8b[jb * 256 + h];
                float a5[8], a8[8];
                unpack8(w5, a5);
                unpack8(w8, a8);
#pragma unroll
                for (int q = 0; q < 8; ++q) {
                    const float4 v4 = *(const float4*)&aux_s[jb * 8 + q][0];
                    const float4 s4 = *(const float4*)&hsh_s[jb * 8 + q][0];
                    const float vv[4] = {v4.x, v4.y, v4.z, v4.w};
                    const float sv[4] = {s4.x, s4.y, s4.z, s4.w};
#pragma unroll
                    for (int t = 0; t < TPB; ++t) {
                        eh[t] = fmaf(a5[q], vv[t], eh[t]);
                        fh[t] = fmaf(a8[q], sv[t], fh[t]);
                    }
                }
            }
#pragma unroll
            for (int t = 0; t < TPB; ++t) {
                const float hru_t = tanhf(phu_[t] + eh[t] + fh[t]);
                const float h_ru = (1.f - z_ru[t]) * phr[t] + z_ru[t] * hru_t;
                if (val[t]) Sru[(size_t)node[t] * H_DIM + h] = h_ru;
            }
            __syncthreads();
        }
        __threadfence();
        grid.sync();
    }
}

__global__ __launch_bounds__(256) void epilogue_k(
    const float* __restrict__ Sru, const int* __restrict__ is_leaf,
    const float* __restrict__ Vr, const float* __restrict__ br,
    float* __restrict__ out) {
    const int b = blockIdx.x;
    const int h = threadIdx.x;
    float m = -3.402823466e38f;
    for (int n = 0; n < N_NODES; ++n) {
        const float v = Sru[((size_t)b * N_NODES + n) * H_DIM + h];
        if (is_leaf[b * N_NODES + n] != 0) m = fmaxf(m, v);
    }
    __shared__ float hm[H_DIM];
    __shared__ float lg[4];
    hm[h] = m;
    __syncthreads();
    if (h < 4) {
        float acc = br[h];
#pragma unroll 8
        for (int j = 0; j < H_DIM; ++j) acc = fmaf(Vr[h * 256 + j], hm[j], acc);
        lg[h] = acc;
    }
    __syncthreads();
    if (h == 0) {
        const float mx = fmaxf(fmaxf(lg[0], lg[1]), fmaxf(lg[2], lg[3]));
        const float e0 = expf(lg[0] - mx);
        const float e1 = expf(lg[1] - mx);
        const float e2 = expf(lg[2] - mx);
        const float e3 = expf(lg[3] - mx);
        const float s = e0 + e1 + e2 + e3;
        out[b * 4 + 0] = e0 / s;
        out[b * 4 + 1] = e1 / s;
        out[b * 4 + 2] = e2 / s;
        out[b * 4 + 3] = e3 / s;
    }
}

extern "C" void kernel_launch(void* const* d_in, const int* in_sizes, int n_in,
                              void* d_out, int out_size, void* d_ws, size_t ws_size,
                              hipStream_t stream) {
    const float* x      = (const float*)d_in[0];
    const float* Er     = (const float*)d_in[1];
    const float* Wsr_r  = (const float*)d_in[2];
    const float* Usr_r  = (const float*)d_in[3];
    const float* Wsr_z  = (const float*)d_in[4];
    const float* Usr_z  = (const float*)d_in[5];
    const float* Wsr_h  = (const float*)d_in[6];
    const float* Usr_h  = (const float*)d_in[7];
    const float* Wr_r   = (const float*)d_in[8];
    const float* Ur_r   = (const float*)d_in[9];
    const float* Usr2r_r= (const float*)d_in[10];
    const float* Wr_z   = (const float*)d_in[11];
    const float* Ur_z   = (const float*)d_in[12];
    const float* Usr2r_z= (const float*)d_in[13];
    const float* Wr_h   = (const float*)d_in[14];
    const float* Ur_h   = (const float*)d_in[15];
    const float* Usr2r_h= (const float*)d_in[16];
    const float* Vr     = (const float*)d_in[17];
    const float* br     = (const float*)d_in[18];
    const int*   parents= (const int*)d_in[19];
    const int*   is_leaf= (const int*)d_in[20];
    float* out = (float*)d_out;

    float* ws = (float*)d_ws;
    float* xt   = ws;                          // 4096*256  f32
    float* P    = xt + 1048576;                // 4096*1536 f32
    float* Wcat = P + 6291456;                 // 1536*256  f32
    uint4* UTb  = (uint4*)(Wcat + 393216);     // 9*32*256 uint4
    float* Ssh  = (float*)(UTb + 73728);       // 32*128*256 f32
    float* Sru  = Ssh + 1048576;               // 32*128*256 f32
    int*   sched     = (int*)(Sru + 1048576);
    int*   level_off = sched + 4096;

    dim3 blk(256);

    // 1) x_tilde = x @ Er^T   (M=4096, N=256, K=5000) — MFMA bf16
    gemm_mfma_nt<<<dim3(64, 4), blk, 0, stream>>>(x, Er, xt, 5000, 256);

    // 2) Wcat = concat(W) rows; P = xt @ Wcat^T (M=4096, N=1536, K=256)
    const float* Ws6[6] = {Wsr_r, Wsr_z, Wsr_h, Wr_r, Wr_z, Wr_h};
    for (int w = 0; w < 6; ++w)
        (void)hipMemcpyAsync(Wcat + (size_t)w * 65536, Ws6[w],
                             65536 * sizeof(float), hipMemcpyDeviceToDevice,
                             stream);
    gemm_mfma_nt<<<dim3(64, 24), blk, 0, stream>>>(xt, Wcat, P, 256, 1536);

    // 3) bf16-pack transposed U
    transpose_pack_u<<<dim3(32, 9), blk, 0, stream>>>(
        Usr_r, Usr_z, Usr_h, Ur_r, Ur_z, Ur_h, Usr2r_r, Usr2r_z, Usr2r_h, UTb);

    // 4) level schedule
    build_schedule<<<dim3(1), blk, 0, stream>>>(parents, sched, level_off);

    // 5) scan (R5-exact)
    void* args[] = {(void*)&P, (void*)&UTb, (void*)&parents,
                    (void*)&sched, (void*)&level_off,
                    (void*)&Ssh, (void*)&Sru};
    (void)hipLaunchCooperativeKernel((const void*)tree_scan_lp,
                                     dim3(GRID_WGS), blk, args, 0, stream);

    // 6) epilogue
    epilogue_k<<<dim3(B_TREES), blk, 0, stream>>>(Sru, is_leaf, Vr, br, out);
}